// Round 11
// baseline (4094.968 us; speedup 1.0000x reference)
//
#include <hip/hip_runtime.h>
#include <math.h>

// FilterShortRange: stable partition of P pairs by ||Rij|| <= 1.6, plus
// passthrough copies and n_valid.
//
// Output layout (float32, element offsets, P = n_pairs):
//   [0,     3P)  Rij_sr   (compacted, tail zeroed)
//   [3P,    4P)  idx_i_sr (compacted, tail -1)
//   [4P,    5P)  idx_j_sr (compacted, tail -1)
//   [5P,    8P)  Rij      (copy)
//   [8P,    9P)  idx_i    (copy, as float)
//   [9P,   10P)  idx_j    (copy, as float)
//   [10P]        n_valid  (as float)
//
// R10: single-pass fused count+scan+scatter via decoupled lookback with
// atomic-ticket block renumbering (deadlock-free: blocks only wait on
// smaller tickets, which started earlier). Valid outputs written directly
// (stable compaction writes are quasi-coalesced — R9 proved LDS staging
// buys nothing). Tail constants (need global n_valid) written by a second
// small kernel. Removes count kernel's 240 MB re-read + 2 launches.
// R11: identical resubmit (R10 never ran — GPU acquisition timeout).

#define BLOCK 256
#define VPT 4
#define CHUNK (BLOCK * VPT)
#define TAIL_GRID 2048

typedef float vf4 __attribute__((ext_vector_type(4)));
typedef int vi4 __attribute__((ext_vector_type(4)));
typedef unsigned long long u64;

__device__ __forceinline__ bool short_mask(float x, float y, float z) {
    // Must bit-match jnp.linalg.norm(Rij,axis=-1) <= 1.6 in f32 (verified
    // absmax==0.0 in rounds 1 and 9 — keep byte-identical).
    float s = x * x + y * y + z * z;
    return sqrtf(s) <= 1.6f;
}

// zero the lookback state + ticket (d_ws is re-poisoned 0xAA every launch)
__global__ void init_kernel(u64* __restrict__ state,
                            unsigned int* __restrict__ ticket, int nb) {
    int i = blockIdx.x * blockDim.x + threadIdx.x;
    if (i < nb) state[i] = 0ull;
    if (i == 0) ticket[0] = 0u;
}

__global__ __launch_bounds__(BLOCK) void fused_kernel(
    const float* __restrict__ Rij, const int* __restrict__ idx_i,
    const int* __restrict__ idx_j, u64* __restrict__ state,
    unsigned int* __restrict__ ticket, int* __restrict__ nvalid_ws,
    float* __restrict__ out, int P, int nb) {
    __shared__ unsigned int s_bid;
    __shared__ int wsums[BLOCK / 64];
    __shared__ int s_excl;

    int tid = threadIdx.x;
    int lane = tid & 63, wid = tid >> 6;

    // dynamic block id: monotone start order => lookback is deadlock-free
    if (tid == 0) s_bid = atomicAdd(ticket, 1u);
    __syncthreads();
    int bid = (int)s_bid;
    int e0 = bid * CHUNK + tid * VPT;

    float x[VPT], y[VPT], z[VPT];
    int ii[VPT], jj[VPT];
    bool m[VPT];

    if (e0 + VPT <= P) {
        const vf4* R4 = (const vf4*)Rij + (e0 * 3) / 4;
        vf4 a = R4[0], c = R4[1], d = R4[2];
        x[0] = a.x; y[0] = a.y; z[0] = a.z;
        x[1] = a.w; y[1] = c.x; z[1] = c.y;
        x[2] = c.z; y[2] = c.w; z[2] = d.x;
        x[3] = d.y; y[3] = d.z; z[3] = d.w;
        vi4 vi = *((const vi4*)idx_i + e0 / 4);
        vi4 vj = *((const vi4*)idx_j + e0 / 4);
        ii[0] = vi.x; ii[1] = vi.y; ii[2] = vi.z; ii[3] = vi.w;
        jj[0] = vj.x; jj[1] = vj.y; jj[2] = vj.z; jj[3] = vj.w;
        for (int j = 0; j < VPT; ++j) m[j] = short_mask(x[j], y[j], z[j]);
        // long-range passthrough, vectorized nontemporal
        vf4* lrR = (vf4*)(out + 5LL * P) + (e0 * 3) / 4;
        __builtin_nontemporal_store(a, lrR + 0);
        __builtin_nontemporal_store(c, lrR + 1);
        __builtin_nontemporal_store(d, lrR + 2);
        vf4 fi = {(float)ii[0], (float)ii[1], (float)ii[2], (float)ii[3]};
        vf4 fj = {(float)jj[0], (float)jj[1], (float)jj[2], (float)jj[3]};
        __builtin_nontemporal_store(fi, (vf4*)(out + 8LL * P) + e0 / 4);
        __builtin_nontemporal_store(fj, (vf4*)(out + 9LL * P) + e0 / 4);
    } else {
        for (int j = 0; j < VPT; ++j) {
            int p = e0 + j;
            if (p < P) {
                x[j] = Rij[3 * p]; y[j] = Rij[3 * p + 1]; z[j] = Rij[3 * p + 2];
                ii[j] = idx_i[p]; jj[j] = idx_j[p];
                m[j] = short_mask(x[j], y[j], z[j]);
                out[5LL * P + 3 * p] = x[j];
                out[5LL * P + 3 * p + 1] = y[j];
                out[5LL * P + 3 * p + 2] = z[j];
                out[8LL * P + p] = (float)ii[j];
                out[9LL * P + p] = (float)jj[j];
            } else {
                m[j] = false;
            }
        }
    }

    int cnt = (int)m[0] + (int)m[1] + (int)m[2] + (int)m[3];

    // wave-inclusive scan of per-thread counts
    int xs = cnt;
    for (int off = 1; off < 64; off <<= 1) {
        int yv = __shfl_up(xs, off);
        if (lane >= off) xs += yv;
    }
    int waveExcl = xs - cnt;
    if (lane == 63) wsums[wid] = xs;
    __syncthreads();  // (A) wsums ready
    int wpre = 0;
    for (int w = 0; w < wid; ++w) wpre += wsums[w];
    int cntB = wsums[0] + wsums[1] + wsums[2] + wsums[3];

    // publish aggregate (block 0's aggregate IS its inclusive prefix)
    if (tid == 0) {
        u64 pk = ((u64)cntB << 2) | (bid == 0 ? 2ull : 1ull);
        __hip_atomic_store(&state[bid], pk, __ATOMIC_RELEASE,
                           __HIP_MEMORY_SCOPE_AGENT);
        if (bid == 0) {
            s_excl = 0;
            if (nb == 1) { nvalid_ws[0] = cntB; out[10LL * P] = (float)cntB; }
        }
    }

    // decoupled lookback, wave 0, 64-wide window
    if (wid == 0 && bid > 0) {
        int running = 0;
        int j = bid - 1;
        for (;;) {
            int idx = j - lane;
            int flag; int val;
            if (idx >= 0) {
                u64 v;
                do {
                    v = __hip_atomic_load(&state[idx], __ATOMIC_ACQUIRE,
                                          __HIP_MEMORY_SCOPE_AGENT);
                    if ((v & 3ull) == 0ull) __builtin_amdgcn_s_sleep(1);
                } while ((v & 3ull) == 0ull);
                flag = (int)(v & 3ull);
                val = (int)(v >> 2);
            } else {
                flag = 2; val = 0;  // virtual block -1: prefix 0
            }
            u64 bal = __ballot(flag == 2);
            if (bal) {
                int L = __ffsll((long long)bal) - 1;  // nearest prefix
                int contrib = (lane <= L) ? val : 0;  // lanes<L: agg, L: prefix
                for (int off = 32; off > 0; off >>= 1)
                    contrib += __shfl_down(contrib, off);
                running += __shfl(contrib, 0);
                break;
            } else {
                int contrib = val;
                for (int off = 32; off > 0; off >>= 1)
                    contrib += __shfl_down(contrib, off);
                running += __shfl(contrib, 0);
                j -= 64;
            }
        }
        if (lane == 0) {
            int incl = running + cntB;
            __hip_atomic_store(&state[bid], (((u64)incl) << 2) | 2ull,
                               __ATOMIC_RELEASE, __HIP_MEMORY_SCOPE_AGENT);
            s_excl = running;
            if (bid == nb - 1) {
                nvalid_ws[0] = incl;
                out[10LL * P] = (float)incl;
            }
        }
    }
    __syncthreads();  // (B) s_excl ready

    // valid writes — direct per-thread (quasi-coalesced; proven ≈floor in R1)
    int vbase = s_excl + wpre + waveExcl;
    int thrPre = 0;
    for (int j = 0; j < VPT; ++j) {
        if (m[j]) {
            long long v = vbase + thrPre;
            out[3 * v] = x[j];
            out[3 * v + 1] = y[j];
            out[3 * v + 2] = z[j];
            out[3LL * P + v] = (float)ii[j];
            out[4LL * P + v] = (float)jj[j];
            ++thrPre;
        }
    }
}

// tail constants: [nvalid, P) of the three compacted streams
__global__ __launch_bounds__(BLOCK) void tail_kernel(
    const int* __restrict__ nvalid_ws, float* __restrict__ out, int P) {
    long long nv = nvalid_ws[0];
    long long tail = (long long)P - nv;
    long long stride = (long long)gridDim.x * blockDim.x;
    long long t0 = (long long)blockIdx.x * blockDim.x + threadIdx.x;
    float* r0 = out + 3 * nv;
    for (long long k = t0; k < 3 * tail; k += stride)
        __builtin_nontemporal_store(0.0f, r0 + k);
    float* i0 = out + 3LL * P + nv;
    float* j0 = out + 4LL * P + nv;
    for (long long k = t0; k < tail; k += stride) {
        __builtin_nontemporal_store(-1.0f, i0 + k);
        __builtin_nontemporal_store(-1.0f, j0 + k);
    }
}

extern "C" void kernel_launch(void* const* d_in, const int* in_sizes, int n_in,
                              void* d_out, int out_size, void* d_ws, size_t ws_size,
                              hipStream_t stream) {
    const float* Rij = (const float*)d_in[0];
    const int* idx_i = (const int*)d_in[1];
    const int* idx_j = (const int*)d_in[2];
    int P = in_sizes[1];
    float* out = (float*)d_out;

    int nb = (P + CHUNK - 1) / CHUNK;
    unsigned int* ticket = (unsigned int*)d_ws;          // [0] ticket
    int* nvalid_ws = (int*)d_ws + 1;                     // [1] n_valid
    u64* state = (u64*)((char*)d_ws + 8);                // [8..8+8*nb) lookback

    init_kernel<<<(nb + 255) / 256, 256, 0, stream>>>(state, ticket, nb);
    fused_kernel<<<nb, BLOCK, 0, stream>>>(Rij, idx_i, idx_j, state, ticket,
                                           nvalid_ws, out, P, nb);
    tail_kernel<<<TAIL_GRID, BLOCK, 0, stream>>>(nvalid_ws, out, P);
}